// Round 2
// baseline (423.444 us; speedup 1.0000x reference)
//
#include <hip/hip_runtime.h>

#define EPS 1e-12f
#define NB 4096

// Select element i (0..7) from two float4s holding an 8-wide register-resident row.
__device__ __forceinline__ float sel8(const float4& a, const float4& b, int i) {
    float lo = (i == 0) ? a.x : (i == 1) ? a.y : (i == 2) ? a.z : a.w;
    float hi = (i == 4) ? b.x : (i == 5) ? b.y : (i == 6) ? b.z : b.w;
    return (i < 4) ? lo : hi;
}

__device__ __forceinline__ float lut_eval(int arc, float x_t, float x_c,
                                          const float* __restrict__ values,
                                          const float* __restrict__ t_table,
                                          const float* __restrict__ c_table,
                                          const int*   __restrict__ dims) {
    const int2 d = ((const int2*)dims)[arc];
    const int td = d.x, cd = d.y;

    const float4* tt = (const float4*)(t_table + (size_t)arc * 8);
    float4 ta = tt[0], tb = tt[1];
    const float4* ct = (const float4*)(c_table + (size_t)arc * 8);
    float4 ca = ct[0], cb = ct[1];

    // searchsorted side='right' over strictly increasing table = count of (tbl <= x)
    int ss_t = (ta.x <= x_t) + (ta.y <= x_t) + (ta.z <= x_t) + (ta.w <= x_t)
             + (tb.x <= x_t) + (tb.y <= x_t) + (tb.z <= x_t) + (tb.w <= x_t);
    int ss_c = (ca.x <= x_c) + (ca.y <= x_c) + (ca.z <= x_c) + (ca.w <= x_c)
             + (cb.x <= x_c) + (cb.y <= x_c) + (cb.z <= x_c) + (cb.w <= x_c);

    int max_t = max(td - 1, 0);
    int max_c = max(cd - 1, 0);
    int t_hi = min(max(ss_t, 1), max_t);
    int c_hi = min(max(ss_c, 1), max_c);
    int t_lo = max(t_hi - 1, 0);
    int c_lo = max(c_hi - 1, 0);

    float t0 = sel8(ta, tb, t_lo), t1 = sel8(ta, tb, t_hi);
    float c0 = sel8(ca, cb, c_lo), c1 = sel8(ca, cb, c_hi);

    float ti = t1 - t0, ci = c1 - c0;
    float xt = fminf(fmaxf(x_t, t0), t1);
    float xc = fminf(fmaxf(x_c, c0), c1);
    float ti_s = (fabsf(ti) < EPS) ? EPS : ti;
    float ci_s = (fabsf(ci) < EPS) ? EPS : ci;
    float ft = fminf(fmaxf((xt - t0) / ti_s, 0.f), 1.f);
    float fc = fminf(fmaxf((xc - c0) / ci_s, 0.f), 1.f);

    bool is2d = (td > 1) && (cd > 1);
    bool is1t = (td > 1) && (cd <= 1);
    bool is1c = (td <= 1) && (cd > 1);
    bool valid = (td > 0) && (cd > 0);

    int i00 = is2d ? (t_lo * cd + c_lo) : is1t ? t_lo : is1c ? c_lo : 0;
    int i01 = is2d ? (t_lo * cd + c_hi) : is1c ? c_hi : i00;
    int i10 = is2d ? (t_hi * cd + c_lo) : is1t ? t_hi : i00;
    int i11 = is2d ? (t_hi * cd + c_hi) : i00;

    const float* vrow = values + (size_t)arc * 64;
    float v00 = vrow[i00];
    float v01 = vrow[i01];
    float v10 = vrow[i10];
    float v11 = vrow[i11];

    float wa = (t1 - xt) * (c1 - xc);
    float wb = (t1 - xt) * (xc - c0);
    float wc = (xt - t0) * (c1 - xc);
    float wd = (xt - t0) * (xc - c0);
    float bil = (v00 * wa + v01 * wb + v10 * wc + v11 * wd) / (ti_s * ci_s);

    float lin_t = v00 + (v10 - v00) * ft;
    float lin_c = v00 + (v01 - v00) * fc;

    float r = is2d ? bil : is1t ? lin_t : is1c ? lin_c : v00;
    return valid ? r : 0.0f;
}

// ---------------- direct (fallback) kernel ----------------
__global__ __launch_bounds__(256) void TimingPropagation_35622458753425_kernel(
    const float* __restrict__ x_t_arr, const float* __restrict__ x_c_arr,
    const int* __restrict__ arcs, const float* __restrict__ values,
    const float* __restrict__ t_table, const float* __restrict__ c_table,
    const int* __restrict__ dims, float* __restrict__ out, int B)
{
    int i = blockIdx.x * blockDim.x + threadIdx.x;
    if (i >= B) return;
    out[i] = lut_eval(arcs[i], x_t_arr[i], x_c_arr[i], values, t_table, c_table, dims);
}

// ---------------- bucket-sort pipeline ----------------
__global__ __launch_bounds__(1024) void k_hist(const int* __restrict__ arcs, int B,
                                               int shift, unsigned* __restrict__ hist) {
    __shared__ unsigned lh[NB];
    for (int v = threadIdx.x; v < NB; v += blockDim.x) lh[v] = 0;
    __syncthreads();
    int stride = gridDim.x * blockDim.x;
    for (int i = blockIdx.x * blockDim.x + threadIdx.x; i < B; i += stride)
        atomicAdd(&lh[((unsigned)arcs[i]) >> shift], 1u);
    __syncthreads();
    for (int v = threadIdx.x; v < NB; v += blockDim.x) {
        unsigned c = lh[v];
        if (c) atomicAdd(&hist[v], c);
    }
}

__global__ __launch_bounds__(1024) void k_scan(const unsigned* __restrict__ hist,
                                               unsigned* __restrict__ cursor) {
    __shared__ unsigned part[1024];
    int t = threadIdx.x;
    unsigned h0 = hist[4 * t], h1 = hist[4 * t + 1], h2 = hist[4 * t + 2], h3 = hist[4 * t + 3];
    unsigned s = h0 + h1 + h2 + h3;
    part[t] = s;
    __syncthreads();
    for (int off = 1; off < 1024; off <<= 1) {
        unsigned v = (t >= off) ? part[t - off] : 0u;
        __syncthreads();
        part[t] += v;
        __syncthreads();
    }
    unsigned excl = part[t] - s;  // exclusive prefix over groups of 4
    cursor[4 * t]     = excl;
    cursor[4 * t + 1] = excl + h0;
    cursor[4 * t + 2] = excl + h0 + h1;
    cursor[4 * t + 3] = excl + h0 + h1 + h2;
}

__global__ __launch_bounds__(256) void k_scatter(const float* __restrict__ xt,
                                                 const float* __restrict__ xc,
                                                 const int* __restrict__ arcs, int B,
                                                 int shift, unsigned* __restrict__ cursor,
                                                 float4* __restrict__ pay) {
    int i = blockIdx.x * blockDim.x + threadIdx.x;
    if (i >= B) return;
    int a = arcs[i];
    unsigned pos = atomicAdd(&cursor[((unsigned)a) >> shift], 1u);
    float4 p;
    p.x = xt[i];
    p.y = xc[i];
    p.z = __int_as_float(a);
    p.w = __int_as_float(i);
    pay[pos] = p;
}

__global__ __launch_bounds__(256) void k_compute(const float4* __restrict__ pay, int B,
                                                 const float* __restrict__ values,
                                                 const float* __restrict__ t_table,
                                                 const float* __restrict__ c_table,
                                                 const int* __restrict__ dims,
                                                 float* __restrict__ out) {
    int j = blockIdx.x * blockDim.x + threadIdx.x;
    if (j >= B) return;
    float4 p = pay[j];
    int arc = __float_as_int(p.z);
    int i   = __float_as_int(p.w);
    out[i] = lut_eval(arc, p.x, p.y, values, t_table, c_table, dims);
}

extern "C" void kernel_launch(void* const* d_in, const int* in_sizes, int n_in,
                              void* d_out, int out_size, void* d_ws, size_t ws_size,
                              hipStream_t stream) {
    const float* x_t   = (const float*)d_in[0];
    const float* x_c   = (const float*)d_in[1];
    const int*   arcs  = (const int*)d_in[2];
    const float* vals  = (const float*)d_in[3];
    const float* t_tbl = (const float*)d_in[4];
    const float* c_tbl = (const float*)d_in[5];
    const int*   dims  = (const int*)d_in[6];
    float* out = (float*)d_out;
    int B = in_sizes[0];
    int N = in_sizes[3] / 64;

    size_t need = 32 * 1024 + (size_t)B * 16;
    if (ws_size < need) {
        // fallback: direct gather kernel
        int grid = (B + 255) / 256;
        TimingPropagation_35622458753425_kernel<<<grid, 256, 0, stream>>>(
            x_t, x_c, arcs, vals, t_tbl, c_tbl, dims, out, B);
        return;
    }

    // bucket shift so that (N-1)>>shift < NB
    int shift = 0;
    while ((((unsigned)(N - 1)) >> shift) >= NB) shift++;

    unsigned* hist   = (unsigned*)d_ws;                    // 16 KB
    unsigned* cursor = (unsigned*)((char*)d_ws + 16 * 1024); // 16 KB
    float4*   pay    = (float4*)((char*)d_ws + 32 * 1024); // B*16 B

    hipMemsetAsync(hist, 0, NB * sizeof(unsigned), stream);
    k_hist<<<128, 1024, 0, stream>>>(arcs, B, shift, hist);
    k_scan<<<1, 1024, 0, stream>>>(hist, cursor);
    int grid = (B + 255) / 256;
    k_scatter<<<grid, 256, 0, stream>>>(x_t, x_c, arcs, B, shift, cursor, pay);
    k_compute<<<grid, 256, 0, stream>>>(pay, B, vals, t_tbl, c_tbl, dims, out);
}

// Round 3
// 316.365 us; speedup vs baseline: 1.3385x; 1.3385x over previous
//
#include <hip/hip_runtime.h>

#define EPS 1e-12f
#define VPT 4  // elements per thread

// Select element i (0..7) from two float4s holding an 8-wide register-resident row.
__device__ __forceinline__ float sel8(const float4& a, const float4& b, int i) {
    float lo = (i == 0) ? a.x : (i == 1) ? a.y : (i == 2) ? a.z : a.w;
    float hi = (i == 4) ? b.x : (i == 5) ? b.y : (i == 6) ? b.z : b.w;
    return (i < 4) ? lo : hi;
}

__global__ __launch_bounds__(256) void TimingPropagation_35622458753425_kernel(
    const float* __restrict__ x_t_arr,   // [B]
    const float* __restrict__ x_c_arr,   // [B]
    const int*   __restrict__ arcs,      // [B]
    const float* __restrict__ values,    // [N,64]
    const float* __restrict__ t_table,   // [N,8]
    const float* __restrict__ c_table,   // [N,8]
    const int*   __restrict__ dims,      // [N,2]
    float*       __restrict__ out,       // [B]
    int B)
{
    const int base = (blockIdx.x * blockDim.x + threadIdx.x) * VPT;

    // ---- phase 0: streaming loads (coalesced within the VPT-strided layout) ----
    float x_t[VPT], x_c[VPT];
    int   arc[VPT];
    bool  act[VPT];
#pragma unroll
    for (int k = 0; k < VPT; k++) {
        int i = base + k;
        act[k] = (i < B);
        int ii = act[k] ? i : 0;
        x_t[k] = x_t_arr[ii];
        x_c[k] = x_c_arr[ii];
        arc[k] = arcs[ii];
    }

    // ---- phase 1: all metadata gathers issued back-to-back (max MLP) ----
    int2   d[VPT];
    float4 ta[VPT], tb[VPT], ca[VPT], cb[VPT];
#pragma unroll
    for (int k = 0; k < VPT; k++) {
        int a = arc[k];
        d[k] = ((const int2*)dims)[a];
        const float4* tt = (const float4*)(t_table + (size_t)a * 8);
        ta[k] = tt[0];
        tb[k] = tt[1];
        const float4* ct = (const float4*)(c_table + (size_t)a * 8);
        ca[k] = ct[0];
        cb[k] = ct[1];
    }

    // ---- phase 2: searchsorted + index math, then all value gathers ----
    int t_lo[VPT], t_hi[VPT], c_lo[VPT], c_hi[VPT];
    int i00[VPT], i01[VPT], i10[VPT], i11[VPT];
    bool is2d[VPT], is1t[VPT], is1c[VPT], valid[VPT];
#pragma unroll
    for (int k = 0; k < VPT; k++) {
        float xt = x_t[k], xc = x_c[k];
        int ss_t = (ta[k].x <= xt) + (ta[k].y <= xt) + (ta[k].z <= xt) + (ta[k].w <= xt)
                 + (tb[k].x <= xt) + (tb[k].y <= xt) + (tb[k].z <= xt) + (tb[k].w <= xt);
        int ss_c = (ca[k].x <= xc) + (ca[k].y <= xc) + (ca[k].z <= xc) + (ca[k].w <= xc)
                 + (cb[k].x <= xc) + (cb[k].y <= xc) + (cb[k].z <= xc) + (cb[k].w <= xc);
        int td = d[k].x, cd = d[k].y;
        int max_t = max(td - 1, 0);
        int max_c = max(cd - 1, 0);
        t_hi[k] = min(max(ss_t, 1), max_t);
        c_hi[k] = min(max(ss_c, 1), max_c);
        t_lo[k] = max(t_hi[k] - 1, 0);
        c_lo[k] = max(c_hi[k] - 1, 0);
        is2d[k] = (td > 1) && (cd > 1);
        is1t[k] = (td > 1) && (cd <= 1);
        is1c[k] = (td <= 1) && (cd > 1);
        valid[k] = (td > 0) && (cd > 0);
        i00[k] = is2d[k] ? (t_lo[k] * cd + c_lo[k]) : is1t[k] ? t_lo[k] : is1c[k] ? c_lo[k] : 0;
        i01[k] = is2d[k] ? (t_lo[k] * cd + c_hi[k]) : is1c[k] ? c_hi[k] : i00[k];
        i10[k] = is2d[k] ? (t_hi[k] * cd + c_lo[k]) : is1t[k] ? t_hi[k] : i00[k];
        i11[k] = is2d[k] ? (t_hi[k] * cd + c_hi[k]) : i00[k];
    }

    float v00[VPT], v01[VPT], v10[VPT], v11[VPT];
#pragma unroll
    for (int k = 0; k < VPT; k++) {
        const float* vrow = values + (size_t)arc[k] * 64;
        v00[k] = vrow[i00[k]];
        v01[k] = vrow[i01[k]];
        v10[k] = vrow[i10[k]];
        v11[k] = vrow[i11[k]];
    }

    // ---- phase 3: arithmetic + store ----
#pragma unroll
    for (int k = 0; k < VPT; k++) {
        if (!act[k]) continue;
        float t0 = sel8(ta[k], tb[k], t_lo[k]), t1 = sel8(ta[k], tb[k], t_hi[k]);
        float c0 = sel8(ca[k], cb[k], c_lo[k]), c1 = sel8(ca[k], cb[k], c_hi[k]);
        float ti = t1 - t0, ci = c1 - c0;
        float xt = fminf(fmaxf(x_t[k], t0), t1);
        float xc = fminf(fmaxf(x_c[k], c0), c1);
        float ti_s = (fabsf(ti) < EPS) ? EPS : ti;
        float ci_s = (fabsf(ci) < EPS) ? EPS : ci;
        float ft = fminf(fmaxf((xt - t0) / ti_s, 0.f), 1.f);
        float fc = fminf(fmaxf((xc - c0) / ci_s, 0.f), 1.f);

        float wa = (t1 - xt) * (c1 - xc);
        float wb = (t1 - xt) * (xc - c0);
        float wc = (xt - t0) * (c1 - xc);
        float wd = (xt - t0) * (xc - c0);
        float bil = (v00[k] * wa + v01[k] * wb + v10[k] * wc + v11[k] * wd) / (ti_s * ci_s);

        float lin_t = v00[k] + (v10[k] - v00[k]) * ft;
        float lin_c = v00[k] + (v01[k] - v00[k]) * fc;

        float r = is2d[k] ? bil : is1t[k] ? lin_t : is1c[k] ? lin_c : v00[k];
        out[base + k] = valid[k] ? r : 0.0f;
    }
}

extern "C" void kernel_launch(void* const* d_in, const int* in_sizes, int n_in,
                              void* d_out, int out_size, void* d_ws, size_t ws_size,
                              hipStream_t stream) {
    const float* x_t   = (const float*)d_in[0];
    const float* x_c   = (const float*)d_in[1];
    const int*   arcs  = (const int*)d_in[2];
    const float* vals  = (const float*)d_in[3];
    const float* t_tbl = (const float*)d_in[4];
    const float* c_tbl = (const float*)d_in[5];
    const int*   dims  = (const int*)d_in[6];
    float* out = (float*)d_out;
    int B = in_sizes[0];
    int block = 256;
    int elems_per_block = block * VPT;
    int grid = (B + elems_per_block - 1) / elems_per_block;
    TimingPropagation_35622458753425_kernel<<<grid, block, 0, stream>>>(
        x_t, x_c, arcs, vals, t_tbl, c_tbl, dims, out, B);
}

// Round 4
// 292.945 us; speedup vs baseline: 1.4455x; 1.0799x over previous
//
#include <hip/hip_runtime.h>

#define EPS 1e-12f

// Select element i (0..7) from two float4s holding an 8-wide register-resident row.
__device__ __forceinline__ float sel8(const float4& a, const float4& b, int i) {
    float lo = (i == 0) ? a.x : (i == 1) ? a.y : (i == 2) ? a.z : a.w;
    float hi = (i == 4) ? b.x : (i == 5) ? b.y : (i == 6) ? b.z : b.w;
    return (i < 4) ? lo : hi;
}

__device__ __forceinline__ float lut_eval_core(int arc, float x_t, float x_c,
                                               int td, int cd,
                                               float4 ta, float4 tb, float4 ca, float4 cb,
                                               const float* __restrict__ values) {
    int ss_t = (ta.x <= x_t) + (ta.y <= x_t) + (ta.z <= x_t) + (ta.w <= x_t)
             + (tb.x <= x_t) + (tb.y <= x_t) + (tb.z <= x_t) + (tb.w <= x_t);
    int ss_c = (ca.x <= x_c) + (ca.y <= x_c) + (ca.z <= x_c) + (ca.w <= x_c)
             + (cb.x <= x_c) + (cb.y <= x_c) + (cb.z <= x_c) + (cb.w <= x_c);

    int max_t = max(td - 1, 0);
    int max_c = max(cd - 1, 0);
    int t_hi = min(max(ss_t, 1), max_t);
    int c_hi = min(max(ss_c, 1), max_c);
    int t_lo = max(t_hi - 1, 0);
    int c_lo = max(c_hi - 1, 0);

    float t0 = sel8(ta, tb, t_lo), t1 = sel8(ta, tb, t_hi);
    float c0 = sel8(ca, cb, c_lo), c1 = sel8(ca, cb, c_hi);

    float ti = t1 - t0, ci = c1 - c0;
    float xt = fminf(fmaxf(x_t, t0), t1);
    float xc = fminf(fmaxf(x_c, c0), c1);
    float ti_s = (fabsf(ti) < EPS) ? EPS : ti;
    float ci_s = (fabsf(ci) < EPS) ? EPS : ci;
    float ft = fminf(fmaxf((xt - t0) / ti_s, 0.f), 1.f);
    float fc = fminf(fmaxf((xc - c0) / ci_s, 0.f), 1.f);

    bool is2d = (td > 1) && (cd > 1);
    bool is1t = (td > 1) && (cd <= 1);
    bool is1c = (td <= 1) && (cd > 1);
    bool valid = (td > 0) && (cd > 0);

    int i00 = is2d ? (t_lo * cd + c_lo) : is1t ? t_lo : is1c ? c_lo : 0;
    int i01 = is2d ? (t_lo * cd + c_hi) : is1c ? c_hi : i00;
    int i10 = is2d ? (t_hi * cd + c_lo) : is1t ? t_hi : i00;
    int i11 = is2d ? (t_hi * cd + c_hi) : i00;

    const float* vrow = values + (size_t)arc * 64;
    float v00 = vrow[i00];
    float v01 = vrow[i01];
    float v10 = vrow[i10];
    float v11 = vrow[i11];

    float wa = (t1 - xt) * (c1 - xc);
    float wb = (t1 - xt) * (xc - c0);
    float wc = (xt - t0) * (c1 - xc);
    float wd = (xt - t0) * (xc - c0);
    float bil = (v00 * wa + v01 * wb + v10 * wc + v11 * wd) / (ti_s * ci_s);

    float lin_t = v00 + (v10 - v00) * ft;
    float lin_c = v00 + (v01 - v00) * fc;

    float r = is2d ? bil : is1t ? lin_t : is1c ? lin_c : v00;
    return valid ? r : 0.0f;
}

// ---- repack: interleave t_tbl|c_tbl into one 64B record/arc; dims -> nibble-packed byte ----
__global__ __launch_bounds__(256) void k_repack(const float* __restrict__ t_table,
                                                const float* __restrict__ c_table,
                                                const int* __restrict__ dims,
                                                float4* __restrict__ packed,   // [N*4]
                                                unsigned char* __restrict__ dims8, // [N] or null
                                                int N) {
    int a = blockIdx.x * blockDim.x + threadIdx.x;
    if (a >= N) return;
    const float4* tt = (const float4*)(t_table + (size_t)a * 8);
    const float4* cc = (const float4*)(c_table + (size_t)a * 8);
    float4* dst = packed + (size_t)a * 4;
    dst[0] = tt[0];
    dst[1] = tt[1];
    dst[2] = cc[0];
    dst[3] = cc[1];
    if (dims8) {
        int2 d = ((const int2*)dims)[a];
        dims8[a] = (unsigned char)((d.x & 0xF) | ((d.y & 0xF) << 4));
    }
}

// ---- main kernel, packed tables + packed dims ----
__global__ __launch_bounds__(256) void k_main_d8(
    const float* __restrict__ x_t_arr, const float* __restrict__ x_c_arr,
    const int* __restrict__ arcs, const float* __restrict__ values,
    const float4* __restrict__ packed, const unsigned char* __restrict__ dims8,
    float* __restrict__ out, int B)
{
    int i = blockIdx.x * blockDim.x + threadIdx.x;
    if (i >= B) return;
    float x_t = x_t_arr[i];
    float x_c = x_c_arr[i];
    int arc = arcs[i];
    unsigned char dp = dims8[arc];
    int td = dp & 0xF, cd = dp >> 4;
    const float4* rec = packed + (size_t)arc * 4;
    float4 ta = rec[0], tb = rec[1], ca = rec[2], cb = rec[3];
    out[i] = lut_eval_core(arc, x_t, x_c, td, cd, ta, tb, ca, cb, values);
}

// ---- main kernel, packed tables + original dims ----
__global__ __launch_bounds__(256) void k_main_d32(
    const float* __restrict__ x_t_arr, const float* __restrict__ x_c_arr,
    const int* __restrict__ arcs, const float* __restrict__ values,
    const float4* __restrict__ packed, const int* __restrict__ dims,
    float* __restrict__ out, int B)
{
    int i = blockIdx.x * blockDim.x + threadIdx.x;
    if (i >= B) return;
    float x_t = x_t_arr[i];
    float x_c = x_c_arr[i];
    int arc = arcs[i];
    int2 d = ((const int2*)dims)[arc];
    const float4* rec = packed + (size_t)arc * 4;
    float4 ta = rec[0], tb = rec[1], ca = rec[2], cb = rec[3];
    out[i] = lut_eval_core(arc, x_t, x_c, d.x, d.y, ta, tb, ca, cb, values);
}

// ---- fallback: fully direct ----
__global__ __launch_bounds__(256) void TimingPropagation_35622458753425_kernel(
    const float* __restrict__ x_t_arr, const float* __restrict__ x_c_arr,
    const int* __restrict__ arcs, const float* __restrict__ values,
    const float* __restrict__ t_table, const float* __restrict__ c_table,
    const int* __restrict__ dims, float* __restrict__ out, int B)
{
    int i = blockIdx.x * blockDim.x + threadIdx.x;
    if (i >= B) return;
    int arc = arcs[i];
    int2 d = ((const int2*)dims)[arc];
    const float4* tt = (const float4*)(t_table + (size_t)arc * 8);
    const float4* cc = (const float4*)(c_table + (size_t)arc * 8);
    float4 ta = tt[0], tb = tt[1], ca = cc[0], cb = cc[1];
    out[i] = lut_eval_core(arc, x_t_arr[i], x_c_arr[i], d.x, d.y, ta, tb, ca, cb, values);
}

extern "C" void kernel_launch(void* const* d_in, const int* in_sizes, int n_in,
                              void* d_out, int out_size, void* d_ws, size_t ws_size,
                              hipStream_t stream) {
    const float* x_t   = (const float*)d_in[0];
    const float* x_c   = (const float*)d_in[1];
    const int*   arcs  = (const int*)d_in[2];
    const float* vals  = (const float*)d_in[3];
    const float* t_tbl = (const float*)d_in[4];
    const float* c_tbl = (const float*)d_in[5];
    const int*   dims  = (const int*)d_in[6];
    float* out = (float*)d_out;
    int B = in_sizes[0];
    int N = in_sizes[3] / 64;

    size_t need_tc = (size_t)N * 64;        // packed t|c records
    size_t need_d8 = need_tc + (size_t)N;   // + nibble dims

    int gridB = (B + 255) / 256;
    int gridN = (N + 255) / 256;

    if (ws_size >= need_d8) {
        float4* packed = (float4*)d_ws;
        unsigned char* dims8 = (unsigned char*)d_ws + need_tc;
        k_repack<<<gridN, 256, 0, stream>>>(t_tbl, c_tbl, dims, packed, dims8, N);
        k_main_d8<<<gridB, 256, 0, stream>>>(x_t, x_c, arcs, vals, packed, dims8, out, B);
    } else if (ws_size >= need_tc) {
        float4* packed = (float4*)d_ws;
        k_repack<<<gridN, 256, 0, stream>>>(t_tbl, c_tbl, dims, packed, nullptr, N);
        k_main_d32<<<gridB, 256, 0, stream>>>(x_t, x_c, arcs, vals, packed, dims, out, B);
    } else {
        TimingPropagation_35622458753425_kernel<<<gridB, 256, 0, stream>>>(
            x_t, x_c, arcs, vals, t_tbl, c_tbl, dims, out, B);
    }
}

// Round 5
// 279.849 us; speedup vs baseline: 1.5131x; 1.0468x over previous
//
#include <hip/hip_runtime.h>

#define EPS 1e-12f

// Select element i (0..7) from two float4s holding an 8-wide register-resident row.
__device__ __forceinline__ float sel8(const float4& a, const float4& b, int i) {
    float lo = (i == 0) ? a.x : (i == 1) ? a.y : (i == 2) ? a.z : a.w;
    float hi = (i == 4) ? b.x : (i == 5) ? b.y : (i == 6) ? b.z : b.w;
    return (i < 4) ? lo : hi;
}

// ---- repack: interleave t_tbl|c_tbl into one 64B record/arc; dims -> nibble-packed byte ----
__global__ __launch_bounds__(256) void k_repack(const float* __restrict__ t_table,
                                                const float* __restrict__ c_table,
                                                const int* __restrict__ dims,
                                                float4* __restrict__ packed,       // [N*4]
                                                unsigned char* __restrict__ dims8, // [N]
                                                int N) {
    int a = blockIdx.x * blockDim.x + threadIdx.x;
    if (a >= N) return;
    const float4* tt = (const float4*)(t_table + (size_t)a * 8);
    const float4* cc = (const float4*)(c_table + (size_t)a * 8);
    float4* dst = packed + (size_t)a * 4;
    dst[0] = tt[0];
    dst[1] = tt[1];
    dst[2] = cc[0];
    dst[3] = cc[1];
    int2 d = ((const int2*)dims)[a];
    dims8[a] = (unsigned char)((d.x & 0xF) | ((d.y & 0xF) << 4));
}

// ---- main kernel: dims-first early-out, packed record, unified value gather ----
__global__ __launch_bounds__(256) void k_main_d8(
    const float* __restrict__ x_t_arr, const float* __restrict__ x_c_arr,
    const int* __restrict__ arcs, const float* __restrict__ values,
    const float4* __restrict__ packed, const unsigned char* __restrict__ dims8,
    float* __restrict__ out, int B)
{
    int i = blockIdx.x * blockDim.x + threadIdx.x;
    if (i >= B) return;
    float x_t = x_t_arr[i];
    float x_c = x_c_arr[i];
    int arc = arcs[i];

    // dims first (tiny L2-resident table) -> skip all heavy gathers for invalid arcs (~21%)
    unsigned char dp = dims8[arc];
    int td = dp & 0xF, cd = dp >> 4;
    if (td == 0 || cd == 0) { out[i] = 0.0f; return; }

    const float4* rec = packed + (size_t)arc * 4;
    float4 ta = rec[0], tb = rec[1], ca = rec[2], cb = rec[3];

    int ss_t = (ta.x <= x_t) + (ta.y <= x_t) + (ta.z <= x_t) + (ta.w <= x_t)
             + (tb.x <= x_t) + (tb.y <= x_t) + (tb.z <= x_t) + (tb.w <= x_t);
    int ss_c = (ca.x <= x_c) + (ca.y <= x_c) + (ca.z <= x_c) + (ca.w <= x_c)
             + (cb.x <= x_c) + (cb.y <= x_c) + (cb.z <= x_c) + (cb.w <= x_c);

    int max_t = max(td - 1, 0);
    int max_c = max(cd - 1, 0);
    int t_hi = min(max(ss_t, 1), max_t);
    int c_hi = min(max(ss_c, 1), max_c);
    int t_lo = max(t_hi - 1, 0);
    int c_lo = max(c_hi - 1, 0);

    float t0 = sel8(ta, tb, t_lo), t1 = sel8(ta, tb, t_hi);
    float c0 = sel8(ca, cb, c_lo), c1 = sel8(ca, cb, c_hi);

    float ti = t1 - t0, ci = c1 - c0;
    float xt = fminf(fmaxf(x_t, t0), t1);
    float xc = fminf(fmaxf(x_c, c0), c1);
    float ti_s = (fabsf(ti) < EPS) ? EPS : ti;
    float ci_s = (fabsf(ci) < EPS) ? EPS : ci;
    float ft = fminf(fmaxf((xt - t0) / ti_s, 0.f), 1.f);
    float fc = fminf(fmaxf((xc - c0) / ci_s, 0.f), 1.f);

    bool is2d = (td > 1) && (cd > 1);
    bool is1t = (td > 1) && (cd <= 1);
    bool is1c = (td <= 1) && (cd > 1);

    int i00 = is2d ? (t_lo * cd + c_lo) : is1t ? t_lo : is1c ? c_lo : 0;
    int i01 = is2d ? (t_lo * cd + c_hi) : is1c ? c_hi : i00;
    int i10 = is2d ? (t_hi * cd + c_lo) : is1t ? t_hi : i00;
    int i11 = is2d ? (t_hi * cd + c_hi) : i00;

    const float* vrow = values + (size_t)arc * 64;
    float v00 = vrow[i00];
    float v01 = vrow[i01];
    float v10 = vrow[i10];
    float v11 = vrow[i11];

    float wa = (t1 - xt) * (c1 - xc);
    float wb = (t1 - xt) * (xc - c0);
    float wc = (xt - t0) * (c1 - xc);
    float wd = (xt - t0) * (xc - c0);
    float bil = (v00 * wa + v01 * wb + v10 * wc + v11 * wd) / (ti_s * ci_s);

    float lin_t = v00 + (v10 - v00) * ft;
    float lin_c = v00 + (v01 - v00) * fc;

    out[i] = is2d ? bil : is1t ? lin_t : is1c ? lin_c : v00;
}

// ---- fallback: fully direct (if ws too small) ----
__global__ __launch_bounds__(256) void TimingPropagation_35622458753425_kernel(
    const float* __restrict__ x_t_arr, const float* __restrict__ x_c_arr,
    const int* __restrict__ arcs, const float* __restrict__ values,
    const float* __restrict__ t_table, const float* __restrict__ c_table,
    const int* __restrict__ dims, float* __restrict__ out, int B)
{
    int i = blockIdx.x * blockDim.x + threadIdx.x;
    if (i >= B) return;
    int arc = arcs[i];
    int2 d = ((const int2*)dims)[arc];
    int td = d.x, cd = d.y;
    if (td == 0 || cd == 0) { out[i] = 0.0f; return; }
    float x_t = x_t_arr[i], x_c = x_c_arr[i];
    const float4* tt = (const float4*)(t_table + (size_t)arc * 8);
    const float4* cc = (const float4*)(c_table + (size_t)arc * 8);
    float4 ta = tt[0], tb = tt[1], ca = cc[0], cb = cc[1];

    int ss_t = (ta.x <= x_t) + (ta.y <= x_t) + (ta.z <= x_t) + (ta.w <= x_t)
             + (tb.x <= x_t) + (tb.y <= x_t) + (tb.z <= x_t) + (tb.w <= x_t);
    int ss_c = (ca.x <= x_c) + (ca.y <= x_c) + (ca.z <= x_c) + (ca.w <= x_c)
             + (cb.x <= x_c) + (cb.y <= x_c) + (cb.z <= x_c) + (cb.w <= x_c);
    int t_hi = min(max(ss_t, 1), max(td - 1, 0));
    int c_hi = min(max(ss_c, 1), max(cd - 1, 0));
    int t_lo = max(t_hi - 1, 0);
    int c_lo = max(c_hi - 1, 0);
    float t0 = sel8(ta, tb, t_lo), t1 = sel8(ta, tb, t_hi);
    float c0 = sel8(ca, cb, c_lo), c1 = sel8(ca, cb, c_hi);
    float ti = t1 - t0, ci = c1 - c0;
    float xt = fminf(fmaxf(x_t, t0), t1);
    float xc = fminf(fmaxf(x_c, c0), c1);
    float ti_s = (fabsf(ti) < EPS) ? EPS : ti;
    float ci_s = (fabsf(ci) < EPS) ? EPS : ci;
    float ft = fminf(fmaxf((xt - t0) / ti_s, 0.f), 1.f);
    float fc = fminf(fmaxf((xc - c0) / ci_s, 0.f), 1.f);
    bool is2d = (td > 1) && (cd > 1);
    bool is1t = (td > 1) && (cd <= 1);
    bool is1c = (td <= 1) && (cd > 1);
    int i00 = is2d ? (t_lo * cd + c_lo) : is1t ? t_lo : is1c ? c_lo : 0;
    int i01 = is2d ? (t_lo * cd + c_hi) : is1c ? c_hi : i00;
    int i10 = is2d ? (t_hi * cd + c_lo) : is1t ? t_hi : i00;
    int i11 = is2d ? (t_hi * cd + c_hi) : i00;
    const float* vrow = values + (size_t)arc * 64;
    float v00 = vrow[i00], v01 = vrow[i01], v10 = vrow[i10], v11 = vrow[i11];
    float wa = (t1 - xt) * (c1 - xc);
    float wb = (t1 - xt) * (xc - c0);
    float wc = (xt - t0) * (c1 - xc);
    float wd = (xt - t0) * (xc - c0);
    float bil = (v00 * wa + v01 * wb + v10 * wc + v11 * wd) / (ti_s * ci_s);
    float lin_t = v00 + (v10 - v00) * ft;
    float lin_c = v00 + (v01 - v00) * fc;
    out[i] = is2d ? bil : is1t ? lin_t : is1c ? lin_c : v00;
}

extern "C" void kernel_launch(void* const* d_in, const int* in_sizes, int n_in,
                              void* d_out, int out_size, void* d_ws, size_t ws_size,
                              hipStream_t stream) {
    const float* x_t   = (const float*)d_in[0];
    const float* x_c   = (const float*)d_in[1];
    const int*   arcs  = (const int*)d_in[2];
    const float* vals  = (const float*)d_in[3];
    const float* t_tbl = (const float*)d_in[4];
    const float* c_tbl = (const float*)d_in[5];
    const int*   dims  = (const int*)d_in[6];
    float* out = (float*)d_out;
    int B = in_sizes[0];
    int N = in_sizes[3] / 64;

    size_t need_tc = (size_t)N * 64;        // packed t|c records
    size_t need_d8 = need_tc + (size_t)N;   // + nibble dims

    int gridB = (B + 255) / 256;
    int gridN = (N + 255) / 256;

    if (ws_size >= need_d8) {
        float4* packed = (float4*)d_ws;
        unsigned char* dims8 = (unsigned char*)d_ws + need_tc;
        k_repack<<<gridN, 256, 0, stream>>>(t_tbl, c_tbl, dims, packed, dims8, N);
        k_main_d8<<<gridB, 256, 0, stream>>>(x_t, x_c, arcs, vals, packed, dims8, out, B);
    } else {
        TimingPropagation_35622458753425_kernel<<<gridB, 256, 0, stream>>>(
            x_t, x_c, arcs, vals, t_tbl, c_tbl, dims, out, B);
    }
}

// Round 7
// 270.903 us; speedup vs baseline: 1.5631x; 1.0330x over previous
//
#include <hip/hip_runtime.h>

#define EPS 1e-12f

typedef float vf4 __attribute__((ext_vector_type(4)));
typedef int   vi2 __attribute__((ext_vector_type(2)));

__device__ __forceinline__ float sel8(const vf4& a, const vf4& b, int i) {
    float lo = (i == 0) ? a.x : (i == 1) ? a.y : (i == 2) ? a.z : a.w;
    float hi = (i == 4) ? b.x : (i == 5) ? b.y : (i == 6) ? b.z : b.w;
    return (i < 4) ? lo : hi;
}

__device__ __forceinline__ float sel4(const vf4& q, int i) {
    return (i == 0) ? q.x : (i == 1) ? q.y : (i == 2) ? q.z : q.w;
}

// ---- repack: interleave t_tbl|c_tbl into one 64B record/arc; dims -> nibble-packed byte ----
__global__ __launch_bounds__(256) void k_repack(const float* __restrict__ t_table,
                                                const float* __restrict__ c_table,
                                                const int* __restrict__ dims,
                                                vf4* __restrict__ packed,          // [N*4]
                                                unsigned char* __restrict__ dims8, // [N]
                                                int N) {
    int a = blockIdx.x * blockDim.x + threadIdx.x;
    if (a >= N) return;
    const vf4* tt = (const vf4*)(t_table + (size_t)a * 8);
    const vf4* cc = (const vf4*)(c_table + (size_t)a * 8);
    vf4 t0 = __builtin_nontemporal_load(tt);
    vf4 t1 = __builtin_nontemporal_load(tt + 1);
    vf4 c0 = __builtin_nontemporal_load(cc);
    vf4 c1 = __builtin_nontemporal_load(cc + 1);
    vf4* dst = packed + (size_t)a * 4;
    dst[0] = t0;
    dst[1] = t1;
    dst[2] = c0;
    dst[3] = c1;
    vi2 d = __builtin_nontemporal_load((const vi2*)dims + a);
    dims8[a] = (unsigned char)((d.x & 0xF) | ((d.y & 0xF) << 4));
}

// ---- main kernel: dims-gated, packed record, paired aligned value quads, NT streaming ----
__global__ __launch_bounds__(256) void k_main_d8(
    const float* __restrict__ x_t_arr, const float* __restrict__ x_c_arr,
    const int* __restrict__ arcs, const float* __restrict__ values,
    const vf4* __restrict__ packed, const unsigned char* __restrict__ dims8,
    float* __restrict__ out, int B)
{
    int i = blockIdx.x * blockDim.x + threadIdx.x;
    if (i >= B) return;
    float x_t = __builtin_nontemporal_load(x_t_arr + i);
    float x_c = __builtin_nontemporal_load(x_c_arr + i);
    int arc = __builtin_nontemporal_load(arcs + i);

    // dims first (L2-resident 0.5 MB) -> skip all heavy gathers for invalid arcs (~21%)
    unsigned char dp = dims8[arc];
    int td = dp & 0xF, cd = dp >> 4;
    if (td == 0 || cd == 0) { __builtin_nontemporal_store(0.0f, out + i); return; }

    const vf4* rec = packed + (size_t)arc * 4;
    vf4 ta = rec[0], tb = rec[1], ca = rec[2], cb = rec[3];

    int ss_t = (ta.x <= x_t) + (ta.y <= x_t) + (ta.z <= x_t) + (ta.w <= x_t)
             + (tb.x <= x_t) + (tb.y <= x_t) + (tb.z <= x_t) + (tb.w <= x_t);
    int ss_c = (ca.x <= x_c) + (ca.y <= x_c) + (ca.z <= x_c) + (ca.w <= x_c)
             + (cb.x <= x_c) + (cb.y <= x_c) + (cb.z <= x_c) + (cb.w <= x_c);

    int t_hi = min(max(ss_t, 1), max(td - 1, 0));
    int c_hi = min(max(ss_c, 1), max(cd - 1, 0));
    int t_lo = max(t_hi - 1, 0);
    int c_lo = max(c_hi - 1, 0);

    float t0 = sel8(ta, tb, t_lo), t1 = sel8(ta, tb, t_hi);
    float c0 = sel8(ca, cb, c_lo), c1 = sel8(ca, cb, c_hi);

    float ti = t1 - t0, ci = c1 - c0;
    float xt = fminf(fmaxf(x_t, t0), t1);
    float xc = fminf(fmaxf(x_c, c0), c1);
    float ti_s = (fabsf(ti) < EPS) ? EPS : ti;
    float ci_s = (fabsf(ci) < EPS) ? EPS : ci;
    float ft = fminf(fmaxf((xt - t0) / ti_s, 0.f), 1.f);
    float fc = fminf(fmaxf((xc - c0) / ci_s, 0.f), 1.f);

    bool is2d = (td > 1) && (cd > 1);
    bool is1t = (td > 1) && (cd <= 1);
    bool is1c = (td <= 1) && (cd > 1);

    // Pair bases: in every mode the needed values are two adjacent pairs.
    //  2D: (i00,i00+1),(i10,i10+1); 1t: (t_lo),(t_hi); 1c: (c_lo,c_lo+1); scalar: (0)
    int iA = is2d ? (t_lo * cd + c_lo) : is1t ? t_lo : is1c ? c_lo : 0;
    int iB = is2d ? (t_hi * cd + c_lo) : is1t ? t_hi : iA;
    int dA = (is2d || is1c) ? 1 : 0;   // v01 = vals[iA + dA]
    int dB = is2d ? 1 : 0;             // v11 = vals[iB + dB]

    const float* vrow = values + (size_t)arc * 64;
    // 16B-aligned quads containing iA / iB (always within the 64-float row)
    int bA = iA & ~3, oA = iA & 3;
    int bB = iB & ~3, oB = iB & 3;
    vf4 qA = *(const vf4*)(vrow + bA);
    vf4 qB = *(const vf4*)(vrow + bB);
    float v00 = sel4(qA, oA);
    float v10 = sel4(qB, oB);
    // fixup loads only when the pair straddles the aligned quad (exec-masked, ~19%)
    float v01 = (oA + dA <= 3) ? sel4(qA, oA + dA) : vrow[iA + dA];
    float v11 = (oB + dB <= 3) ? sel4(qB, oB + dB) : vrow[iB + dB];

    float wa = (t1 - xt) * (c1 - xc);
    float wb = (t1 - xt) * (xc - c0);
    float wc = (xt - t0) * (c1 - xc);
    float wd = (xt - t0) * (xc - c0);
    float bil = (v00 * wa + v01 * wb + v10 * wc + v11 * wd) / (ti_s * ci_s);

    float lin_t = v00 + (v10 - v00) * ft;
    float lin_c = v00 + (v01 - v00) * fc;

    float r = is2d ? bil : is1t ? lin_t : is1c ? lin_c : v00;
    __builtin_nontemporal_store(r, out + i);
}

// ---- fallback: fully direct (if ws too small) ----
__global__ __launch_bounds__(256) void TimingPropagation_35622458753425_kernel(
    const float* __restrict__ x_t_arr, const float* __restrict__ x_c_arr,
    const int* __restrict__ arcs, const float* __restrict__ values,
    const float* __restrict__ t_table, const float* __restrict__ c_table,
    const int* __restrict__ dims, float* __restrict__ out, int B)
{
    int i = blockIdx.x * blockDim.x + threadIdx.x;
    if (i >= B) return;
    int arc = arcs[i];
    int td = dims[2 * arc], cd = dims[2 * arc + 1];
    if (td == 0 || cd == 0) { out[i] = 0.0f; return; }
    float x_t = x_t_arr[i], x_c = x_c_arr[i];
    const vf4* tt = (const vf4*)(t_table + (size_t)arc * 8);
    const vf4* cc = (const vf4*)(c_table + (size_t)arc * 8);
    vf4 ta = tt[0], tb = tt[1], ca = cc[0], cb = cc[1];
    int ss_t = (ta.x <= x_t) + (ta.y <= x_t) + (ta.z <= x_t) + (ta.w <= x_t)
             + (tb.x <= x_t) + (tb.y <= x_t) + (tb.z <= x_t) + (tb.w <= x_t);
    int ss_c = (ca.x <= x_c) + (ca.y <= x_c) + (ca.z <= x_c) + (ca.w <= x_c)
             + (cb.x <= x_c) + (cb.y <= x_c) + (cb.z <= x_c) + (cb.w <= x_c);
    int t_hi = min(max(ss_t, 1), max(td - 1, 0));
    int c_hi = min(max(ss_c, 1), max(cd - 1, 0));
    int t_lo = max(t_hi - 1, 0);
    int c_lo = max(c_hi - 1, 0);
    float t0 = sel8(ta, tb, t_lo), t1 = sel8(ta, tb, t_hi);
    float c0 = sel8(ca, cb, c_lo), c1 = sel8(ca, cb, c_hi);
    float ti = t1 - t0, ci = c1 - c0;
    float xt = fminf(fmaxf(x_t, t0), t1);
    float xc = fminf(fmaxf(x_c, c0), c1);
    float ti_s = (fabsf(ti) < EPS) ? EPS : ti;
    float ci_s = (fabsf(ci) < EPS) ? EPS : ci;
    float ft = fminf(fmaxf((xt - t0) / ti_s, 0.f), 1.f);
    float fc = fminf(fmaxf((xc - c0) / ci_s, 0.f), 1.f);
    bool is2d = (td > 1) && (cd > 1);
    bool is1t = (td > 1) && (cd <= 1);
    bool is1c = (td <= 1) && (cd > 1);
    int i00 = is2d ? (t_lo * cd + c_lo) : is1t ? t_lo : is1c ? c_lo : 0;
    int i01 = is2d ? (t_lo * cd + c_hi) : is1c ? c_hi : i00;
    int i10 = is2d ? (t_hi * cd + c_lo) : is1t ? t_hi : i00;
    int i11 = is2d ? (t_hi * cd + c_hi) : i00;
    const float* vrow = values + (size_t)arc * 64;
    float v00 = vrow[i00], v01 = vrow[i01], v10 = vrow[i10], v11 = vrow[i11];
    float wa = (t1 - xt) * (c1 - xc);
    float wb = (t1 - xt) * (xc - c0);
    float wc = (xt - t0) * (c1 - xc);
    float wd = (xt - t0) * (xc - c0);
    float bil = (v00 * wa + v01 * wb + v10 * wc + v11 * wd) / (ti_s * ci_s);
    float lin_t = v00 + (v10 - v00) * ft;
    float lin_c = v00 + (v01 - v00) * fc;
    out[i] = is2d ? bil : is1t ? lin_t : is1c ? lin_c : v00;
}

extern "C" void kernel_launch(void* const* d_in, const int* in_sizes, int n_in,
                              void* d_out, int out_size, void* d_ws, size_t ws_size,
                              hipStream_t stream) {
    const float* x_t   = (const float*)d_in[0];
    const float* x_c   = (const float*)d_in[1];
    const int*   arcs  = (const int*)d_in[2];
    const float* vals  = (const float*)d_in[3];
    const float* t_tbl = (const float*)d_in[4];
    const float* c_tbl = (const float*)d_in[5];
    const int*   dims  = (const int*)d_in[6];
    float* out = (float*)d_out;
    int B = in_sizes[0];
    int N = in_sizes[3] / 64;

    size_t need_tc = (size_t)N * 64;        // packed t|c records
    size_t need_d8 = need_tc + (size_t)N;   // + nibble dims

    int gridB = (B + 255) / 256;
    int gridN = (N + 255) / 256;

    if (ws_size >= need_d8) {
        vf4* packed = (vf4*)d_ws;
        unsigned char* dims8 = (unsigned char*)d_ws + need_tc;
        k_repack<<<gridN, 256, 0, stream>>>(t_tbl, c_tbl, dims, packed, dims8, N);
        k_main_d8<<<gridB, 256, 0, stream>>>(x_t, x_c, arcs, vals, packed, dims8, out, B);
    } else {
        TimingPropagation_35622458753425_kernel<<<gridB, 256, 0, stream>>>(
            x_t, x_c, arcs, vals, t_tbl, c_tbl, dims, out, B);
    }
}